// Round 2
// baseline (1042.611 us; speedup 1.0000x reference)
//
#include <hip/hip_runtime.h>
#include <hip/hip_fp16.h>

#define B_ 16
#define T_ 256
#define D_ 128
#define H_ 256
#define G3_ 768

__device__ __forceinline__ float fast_rcp(float x) {
#if __has_builtin(__builtin_amdgcn_rcpf)
    return __builtin_amdgcn_rcpf(x);
#else
    return 1.0f / x;
#endif
}
__device__ __forceinline__ float sigmoid_f(float x) {
    return fast_rcp(1.0f + __expf(-x));
}
__device__ __forceinline__ float tanh_f(float x) {
    // tanh(x) = 1 - 2/(1+e^{2x}); e=inf -> 1, e=0 -> -1 (no NaN at extremes)
    float e = __expf(2.0f * x);
    return 1.0f - 2.0f * fast_rcp(1.0f + e);
}

// ---- convert both Whh matrices f32 -> packed half2 [768][128] ----
__global__ void k_cvtw(const float* __restrict__ wa, const float* __restrict__ wb,
                       __half2* __restrict__ oa, __half2* __restrict__ ob) {
    int i = blockIdx.x * 256 + threadIdx.x;
    const int n = G3_ * (H_ / 2); // 98304
    if (i < n) {
        oa[i] = __floats2half2_rn(wa[2 * i], wa[2 * i + 1]);
        ob[i] = __floats2half2_rn(wb[2 * i], wb[2 * i + 1]);
    }
}

// ---- mask precompute: pos[b][s] = first t with targets[b,t]==s (else T) ----
__global__ void k_pos_init(int* __restrict__ pos) {
    pos[blockIdx.x * 256 + threadIdx.x] = T_;
}
__global__ void k_pos_scan(const int* __restrict__ tgt, int* __restrict__ pos) {
    int i = blockIdx.x * 256 + threadIdx.x; // [0, B*T)
    int b = i >> 8, t = i & 255;
    int s = tgt[i] & 255; // targets are a permutation of [0,256); clamp defensively
    atomicMin(&pos[(b << 8) + s], t);
}

// ---- enc_in = inputs @ W_enc^T + b_enc   [B*T,128] x [256,128]^T ----
__global__ __launch_bounds__(256) void k_encA(const float* __restrict__ in,
                                              const float* __restrict__ W,
                                              const float* __restrict__ bias,
                                              float* __restrict__ out) {
    int bt0 = blockIdx.x * 8; // 8 rows per block, same b (T divisible by 8)
    int a = threadIdx.x;
    float bv = bias[a];
    float acc[8];
#pragma unroll
    for (int tt = 0; tt < 8; ++tt) acc[tt] = bv;
    const float* wr = W + a * D_;
    for (int k = 0; k < D_; k += 4) {
        float4 w4 = *(const float4*)(wr + k);
#pragma unroll
        for (int tt = 0; tt < 8; ++tt) {
            float4 x4 = *(const float4*)(in + (bt0 + tt) * D_ + k);
            acc[tt] += w4.x * x4.x + w4.y * x4.y + w4.z * x4.z + w4.w * x4.w;
        }
    }
#pragma unroll
    for (int tt = 0; tt < 8; ++tt) out[(bt0 + tt) * H_ + a] = acc[tt];
}

// ---- x_proj = rows(in) @ Wih^T + bih ; optional teacher-forcing gather ----
__global__ __launch_bounds__(256) void k_proj3(const float* __restrict__ in,
                                               const float* __restrict__ W,
                                               const float* __restrict__ bias,
                                               const int* __restrict__ tgt,
                                               float* __restrict__ out) {
    int bt0 = blockIdx.x * 8;
    int b = bt0 >> 8;
    int a = threadIdx.x;
    const float* rp[8];
#pragma unroll
    for (int tt = 0; tt < 8; ++tt) {
        int t = (bt0 & 255) + tt;
        int tsrc = t;
        if (tgt) tsrc = tgt[(b << 8) + ((t + 255) & 255)] & 255; // roll(targets,1)
        rp[tt] = in + ((b << 8) + tsrc) * H_;
    }
    float acc0[8], acc1[8], acc2[8];
    float b0 = bias[a], b1 = bias[a + 256], b2 = bias[a + 512];
#pragma unroll
    for (int tt = 0; tt < 8; ++tt) { acc0[tt] = b0; acc1[tt] = b1; acc2[tt] = b2; }
    const float* w0 = W + a * H_;
    const float* w1 = W + (a + 256) * H_;
    const float* w2 = W + (a + 512) * H_;
    for (int k = 0; k < H_; k += 4) {
        float4 a4 = *(const float4*)(w0 + k);
        float4 b4 = *(const float4*)(w1 + k);
        float4 c4 = *(const float4*)(w2 + k);
#pragma unroll
        for (int tt = 0; tt < 8; ++tt) {
            float4 x4 = *(const float4*)(rp[tt] + k);
            acc0[tt] += a4.x * x4.x + a4.y * x4.y + a4.z * x4.z + a4.w * x4.w;
            acc1[tt] += b4.x * x4.x + b4.y * x4.y + b4.z * x4.z + b4.w * x4.w;
            acc2[tt] += c4.x * x4.x + c4.y * x4.y + c4.z * x4.z + c4.w * x4.w;
        }
    }
    int base = bt0 * G3_;
#pragma unroll
    for (int tt = 0; tt < 8; ++tt) {
        out[base + tt * G3_ + a] = acc0[tt];
        out[base + tt * G3_ + a + 256] = acc1[tt];
        out[base + tt * G3_ + a + 512] = acc2[tt];
    }
}

// ---- single-row projection (q / k), no bias ----
__global__ __launch_bounds__(256) void k_proj1(const float* __restrict__ in,
                                               const float* __restrict__ W,
                                               float* __restrict__ out) {
    int bt0 = blockIdx.x * 8;
    int a = threadIdx.x;
    float acc[8];
#pragma unroll
    for (int tt = 0; tt < 8; ++tt) acc[tt] = 0.f;
    const float* w0 = W + a * H_;
    for (int k = 0; k < H_; k += 4) {
        float4 w4 = *(const float4*)(w0 + k);
#pragma unroll
        for (int tt = 0; tt < 8; ++tt) {
            float4 x4 = *(const float4*)(in + (bt0 + tt) * H_ + k);
            acc[tt] += w4.x * x4.x + w4.y * x4.y + w4.z * x4.z + w4.w * x4.w;
        }
    }
#pragma unroll
    for (int tt = 0; tt < 8; ++tt) out[(bt0 + tt) * H_ + a] = acc[tt];
}

// ---- GRU: one block per batch, Whh(f16) resident in VGPRs ----
// 512 threads: jj = tid&127 owns hidden pair (2jj,2jj+1); c = tid>>7 owns K-chunk of 64.
__global__ __launch_bounds__(512, 2) void k_gru(const __half2* __restrict__ Wh, // [768][128] packed pairs along K
                                                const float* __restrict__ xproj, // [B,T,768]
                                                const float* __restrict__ bhh,   // [768]
                                                const __half2* __restrict__ h0,  // [B][128] or null (zeros)
                                                float* __restrict__ out,         // [B,T,256]
                                                __half2* __restrict__ hT) {      // [B][128] or null
    __shared__ __half2 sh_h[128];          // h packed (h[2j],h[2j+1])
    __shared__ float sh_part[4][6][128];   // partial dots per K-chunk
    const int b = blockIdx.x;
    const int tid = threadIdx.x;
    const int jj = tid & 127;
    const int c = tid >> 7;

    // rows r=0..5: gate g=r>>1 (r,z,n), hidden j = 2*jj + (r&1)
    __half2 w[6][32];
    float bh[6];
#pragma unroll
    for (int r = 0; r < 6; ++r) {
        const int row = (r >> 1) * 256 + 2 * jj + (r & 1);
        const __half2* p = Wh + row * 128 + c * 32;
#pragma unroll
        for (int i = 0; i < 32; ++i) w[r][i] = p[i];
        bh[r] = bhh[row];
    }

    if (tid < 128) sh_h[tid] = h0 ? h0[b * 128 + tid] : __float2half2_rn(0.f);
    __syncthreads();

    const float* xp = xproj + b * (T_ * G3_);
    float* ob = out + b * (T_ * H_);

    for (int t = 0; t < T_; ++t) {
        const float* xpt = xp + t * G3_;
        float2 gi0 = *(const float2*)(xpt + 2 * jj);
        float2 gi1 = *(const float2*)(xpt + 256 + 2 * jj);
        float2 gi2 = *(const float2*)(xpt + 512 + 2 * jj);

        __half2 hacc[6];
#pragma unroll
        for (int r = 0; r < 6; ++r) hacc[r] = __float2half2_rn(0.f);
        const __half2* hc = sh_h + c * 32;
#pragma unroll
        for (int i = 0; i < 32; ++i) {
            __half2 hv = hc[i];
#pragma unroll
            for (int r = 0; r < 6; ++r) hacc[r] = __hfma2(w[r][i], hv, hacc[r]);
        }
#pragma unroll
        for (int r = 0; r < 6; ++r)
            sh_part[c][r][jj] = __low2float(hacc[r]) + __high2float(hacc[r]);
        __syncthreads();

        if (tid < 128) { // c==0, jj==tid
            float gh[6];
#pragma unroll
            for (int r = 0; r < 6; ++r)
                gh[r] = sh_part[0][r][jj] + sh_part[1][r][jj] + sh_part[2][r][jj] +
                        sh_part[3][r][jj] + bh[r];
            __half2 hold = sh_h[jj];
            float hp0 = __low2float(hold), hp1 = __high2float(hold);
            float r0 = sigmoid_f(gi0.x + gh[0]);
            float r1 = sigmoid_f(gi0.y + gh[1]);
            float z0 = sigmoid_f(gi1.x + gh[2]);
            float z1 = sigmoid_f(gi1.y + gh[3]);
            float n0 = tanh_f(gi2.x + r0 * gh[4]);
            float n1 = tanh_f(gi2.y + r1 * gh[5]);
            float hn0 = (1.f - z0) * n0 + z0 * hp0;
            float hn1 = (1.f - z1) * n1 + z1 * hp1;
            *(float2*)(ob + t * H_ + 2 * jj) = make_float2(hn0, hn1);
            sh_h[jj] = __floats2half2_rn(hn0, hn1);
        }
        __syncthreads();
    }
    if (hT && tid < 128) hT[b * 128 + tid] = sh_h[tid];
}

// ---- transpose k[b][s][a] -> kT[b][a][s] ----
__global__ __launch_bounds__(256) void k_transpose(const float* __restrict__ k_,
                                                   float* __restrict__ kT) {
    __shared__ float tile[64][65];
    int blk = blockIdx.x;
    int b = blk >> 4;
    int ti = (blk >> 2) & 3;
    int tj = blk & 3;
    int lane = threadIdx.x & 63;
    int ty = threadIdx.x >> 6; // 0..3
    const float* kb = k_ + b * (T_ * H_);
    for (int r = ty; r < 64; r += 4)
        tile[r][lane] = kb[(ti * 64 + r) * H_ + tj * 64 + lane];
    __syncthreads();
    float* kTb = kT + b * (T_ * H_);
    for (int r = ty; r < 64; r += 4)
        kTb[(tj * 64 + r) * T_ + ti * 64 + lane] = tile[lane][r];
}

// ---- logits[b,t,s] = mask ? v . tanh(q[b,t,:]+k[b,s,:]) : -1e9 ----
__global__ __launch_bounds__(256) void k_scores(const float* __restrict__ q,
                                                const float* __restrict__ kT,
                                                const float* __restrict__ v,
                                                const int* __restrict__ pos,
                                                float* __restrict__ out) {
    __shared__ float sq[4][256];
    __shared__ float sv[256];
    int blk = blockIdx.x;
    int b = blk >> 6;
    int t0 = (blk & 63) * 4;
    int s = threadIdx.x;
    sv[s] = v[s];
#pragma unroll
    for (int tt = 0; tt < 4; ++tt)
        sq[tt][s] = q[((b << 8) + t0 + tt) * H_ + s];
    __syncthreads();
    int ps = pos[(b << 8) + s];
    float acc[4] = {0.f, 0.f, 0.f, 0.f};
    const float* kTb = kT + b * (T_ * H_);
    for (int a = 0; a < H_; ++a) {
        float kv = kTb[a * T_ + s];
        float va = sv[a];
#pragma unroll
        for (int tt = 0; tt < 4; ++tt) {
            float th = tanh_f(sq[tt][a] + kv);
            acc[tt] += va * th;
        }
    }
#pragma unroll
    for (int tt = 0; tt < 4; ++tt) {
        int t = t0 + tt;
        out[((b << 8) + t) * T_ + s] = (t <= ps) ? acc[tt] : -1.0e9f;
    }
}

extern "C" void kernel_launch(void* const* d_in, const int* in_sizes, int n_in,
                              void* d_out, int out_size, void* d_ws, size_t ws_size,
                              hipStream_t stream) {
    (void)in_sizes; (void)n_in; (void)out_size; (void)ws_size;
    const float* inputs   = (const float*)d_in[0];
    const int* targets    = (const int*)d_in[1];  // harness passes integers as int32
    const float* W_enc   = (const float*)d_in[2];
    const float* b_enc   = (const float*)d_in[3];
    const float* enc_Wih = (const float*)d_in[4];
    const float* enc_Whh = (const float*)d_in[5];
    const float* enc_bih = (const float*)d_in[6];
    const float* enc_bhh = (const float*)d_in[7];
    const float* dec_Wih = (const float*)d_in[8];
    const float* dec_Whh = (const float*)d_in[9];
    const float* dec_bih = (const float*)d_in[10];
    const float* dec_bhh = (const float*)d_in[11];
    const float* Wq = (const float*)d_in[12];
    const float* Wk = (const float*)d_in[13];
    const float* v  = (const float*)d_in[14];
    float* out = (float*)d_out;

    float* ws = (float*)d_ws;
    float* enc_in  = ws;                 // 1,048,576 f
    float* xproj   = ws + 1048576;       // 3,145,728 f (enc then dec; later k/kT)
    float* enc_out = ws + 4194304;       // 1,048,576 f
    float* dec_out = ws + 5242880;       // 1,048,576 f
    __half2* w16e  = (__half2*)(ws + 6291456); // 98,304 dwords
    __half2* w16d  = (__half2*)(ws + 6389760); // 98,304 dwords
    __half2* hT    = (__half2*)(ws + 6488064); // 2,048 dwords
    int* pos       = (int*)(ws + 6490112);     // 4,096 ints
    float* q  = enc_in;          // alias: enc_in dead after dec proj
    float* kk = xproj;           // alias: xproj dead after dec GRU
    float* kT = xproj + 1048576; // alias

    k_cvtw<<<384, 256, 0, stream>>>(enc_Whh, dec_Whh, w16e, w16d);
    k_pos_init<<<16, 256, 0, stream>>>(pos);
    k_pos_scan<<<16, 256, 0, stream>>>(targets, pos);
    k_encA<<<512, 256, 0, stream>>>(inputs, W_enc, b_enc, enc_in);
    k_proj3<<<512, 256, 0, stream>>>(enc_in, enc_Wih, enc_bih, nullptr, xproj);
    k_gru<<<16, 512, 0, stream>>>(w16e, xproj, enc_bhh, nullptr, enc_out, hT);
    k_proj3<<<512, 256, 0, stream>>>(enc_in, dec_Wih, dec_bih, targets, xproj);
    k_gru<<<16, 512, 0, stream>>>(w16d, xproj, dec_bhh, hT, dec_out, nullptr);
    k_proj1<<<512, 256, 0, stream>>>(dec_out, Wq, q);
    k_proj1<<<512, 256, 0, stream>>>(enc_out, Wk, kk);
    k_transpose<<<256, 256, 0, stream>>>(kk, kT);
    k_scores<<<1024, 256, 0, stream>>>(q, kT, v, pos, out);
}

// Round 3
// 934.647 us; speedup vs baseline: 1.1155x; 1.1155x over previous
//
#include <hip/hip_runtime.h>
#include <hip/hip_fp16.h>

#define B_ 16
#define T_ 256
#define D_ 128
#define H_ 256
#define G3_ 768

__device__ __forceinline__ float fast_rcp(float x) {
#if __has_builtin(__builtin_amdgcn_rcpf)
    return __builtin_amdgcn_rcpf(x);
#else
    return 1.0f / x;
#endif
}
__device__ __forceinline__ float sigmoid_f(float x) {
    return fast_rcp(1.0f + __expf(-x));
}
__device__ __forceinline__ float tanh_f(float x) {
    // tanh(x) = 1 - 2/(1+e^{2x}); e=inf -> 1, e=0 -> -1 (no NaN at extremes)
    float e = __expf(2.0f * x);
    return 1.0f - 2.0f * fast_rcp(1.0f + e);
}

// ---- convert both Whh matrices f32 -> packed half2 [768][128] ----
__global__ void k_cvtw(const float* __restrict__ wa, const float* __restrict__ wb,
                       __half2* __restrict__ oa, __half2* __restrict__ ob) {
    int i = blockIdx.x * 256 + threadIdx.x;
    const int n = G3_ * (H_ / 2); // 98304
    if (i < n) {
        oa[i] = __floats2half2_rn(wa[2 * i], wa[2 * i + 1]);
        ob[i] = __floats2half2_rn(wb[2 * i], wb[2 * i + 1]);
    }
}

// ---- mask precompute: pos[b][s] = first t with targets[b,t]==s (else T) ----
__global__ void k_pos_init(int* __restrict__ pos) {
    pos[blockIdx.x * 256 + threadIdx.x] = T_;
}
__global__ void k_pos_scan(const int* __restrict__ tgt, int* __restrict__ pos) {
    int i = blockIdx.x * 256 + threadIdx.x; // [0, B*T)
    int b = i >> 8, t = i & 255;
    int s = tgt[i] & 255; // targets are a permutation of [0,256); clamp defensively
    atomicMin(&pos[(b << 8) + s], t);
}

// ---- enc_in = inputs @ W_enc^T + b_enc   [B*T,128] x [256,128]^T ----
__global__ __launch_bounds__(256) void k_encA(const float* __restrict__ in,
                                              const float* __restrict__ W,
                                              const float* __restrict__ bias,
                                              float* __restrict__ out) {
    int bt0 = blockIdx.x * 8; // 8 rows per block, same b (T divisible by 8)
    int a = threadIdx.x;
    float bv = bias[a];
    float acc[8];
#pragma unroll
    for (int tt = 0; tt < 8; ++tt) acc[tt] = bv;
    const float* wr = W + a * D_;
    for (int k = 0; k < D_; k += 4) {
        float4 w4 = *(const float4*)(wr + k);
#pragma unroll
        for (int tt = 0; tt < 8; ++tt) {
            float4 x4 = *(const float4*)(in + (bt0 + tt) * D_ + k);
            acc[tt] += w4.x * x4.x + w4.y * x4.y + w4.z * x4.z + w4.w * x4.w;
        }
    }
#pragma unroll
    for (int tt = 0; tt < 8; ++tt) out[(bt0 + tt) * H_ + a] = acc[tt];
}

// ---- x_proj = rows(in) @ Wih^T + bih ; optional teacher-forcing gather ----
__global__ __launch_bounds__(256) void k_proj3(const float* __restrict__ in,
                                               const float* __restrict__ W,
                                               const float* __restrict__ bias,
                                               const int* __restrict__ tgt,
                                               float* __restrict__ out) {
    int bt0 = blockIdx.x * 8;
    int b = bt0 >> 8;
    int a = threadIdx.x;
    const float* rp[8];
#pragma unroll
    for (int tt = 0; tt < 8; ++tt) {
        int t = (bt0 & 255) + tt;
        int tsrc = t;
        if (tgt) tsrc = tgt[(b << 8) + ((t + 255) & 255)] & 255; // roll(targets,1)
        rp[tt] = in + ((b << 8) + tsrc) * H_;
    }
    float acc0[8], acc1[8], acc2[8];
    float b0 = bias[a], b1 = bias[a + 256], b2 = bias[a + 512];
#pragma unroll
    for (int tt = 0; tt < 8; ++tt) { acc0[tt] = b0; acc1[tt] = b1; acc2[tt] = b2; }
    const float* w0 = W + a * H_;
    const float* w1 = W + (a + 256) * H_;
    const float* w2 = W + (a + 512) * H_;
    for (int k = 0; k < H_; k += 4) {
        float4 a4 = *(const float4*)(w0 + k);
        float4 b4 = *(const float4*)(w1 + k);
        float4 c4 = *(const float4*)(w2 + k);
#pragma unroll
        for (int tt = 0; tt < 8; ++tt) {
            float4 x4 = *(const float4*)(rp[tt] + k);
            acc0[tt] += a4.x * x4.x + a4.y * x4.y + a4.z * x4.z + a4.w * x4.w;
            acc1[tt] += b4.x * x4.x + b4.y * x4.y + b4.z * x4.z + b4.w * x4.w;
            acc2[tt] += c4.x * x4.x + c4.y * x4.y + c4.z * x4.z + c4.w * x4.w;
        }
    }
    int base = bt0 * G3_;
#pragma unroll
    for (int tt = 0; tt < 8; ++tt) {
        out[base + tt * G3_ + a] = acc0[tt];
        out[base + tt * G3_ + a + 256] = acc1[tt];
        out[base + tt * G3_ + a + 512] = acc2[tt];
    }
}

// ---- single-row projection (q / k), no bias ----
__global__ __launch_bounds__(256) void k_proj1(const float* __restrict__ in,
                                               const float* __restrict__ W,
                                               float* __restrict__ out) {
    int bt0 = blockIdx.x * 8;
    int a = threadIdx.x;
    float acc[8];
#pragma unroll
    for (int tt = 0; tt < 8; ++tt) acc[tt] = 0.f;
    const float* w0 = W + a * H_;
    for (int k = 0; k < H_; k += 4) {
        float4 w4 = *(const float4*)(w0 + k);
#pragma unroll
        for (int tt = 0; tt < 8; ++tt) {
            float4 x4 = *(const float4*)(in + (bt0 + tt) * H_ + k);
            acc[tt] += w4.x * x4.x + w4.y * x4.y + w4.z * x4.z + w4.w * x4.w;
        }
    }
#pragma unroll
    for (int tt = 0; tt < 8; ++tt) out[(bt0 + tt) * H_ + a] = acc[tt];
}

// ---- GRU: one block per batch; thread (j = hidden unit, c = K-half intra-wave) ----
// 512 threads = 8 waves; wave w covers units j = w*32 + (lane&31); c = lane>>5.
// Weights (3 gate rows x 64 half2 per thread = 192 VGPRs) stay architectural via
// __launch_bounds__(512,1). K-reduction via __shfl_xor(32) — no LDS partials.
// Double-buffered sh_h -> exactly one barrier per step.
__global__ __launch_bounds__(512, 1) void k_gru(const __half2* __restrict__ Wh, // [768][128] half2 pairs along K
                                                const float* __restrict__ xproj, // [B,T,768]
                                                const float* __restrict__ bhh,   // [768]
                                                const float* __restrict__ h0,    // [B][256] f32 or null (zeros)
                                                float* __restrict__ out,         // [B,T,256]
                                                float* __restrict__ hT) {        // [B][256] f32 or null
    __shared__ __align__(16) __half sh_h[2][256];
    const int b = blockIdx.x;
    const int tid = threadIdx.x;
    const int lane = tid & 63;
    const int j = (tid >> 6) * 32 + (lane & 31);
    const int c = lane >> 5;

    __half2 w[3][64];
    float bh[3];
#pragma unroll
    for (int r = 0; r < 3; ++r) {
        const int row = r * 256 + j;
        const float4* p = (const float4*)(Wh + row * 128 + c * 64);
#pragma unroll
        for (int i = 0; i < 16; ++i) {
            float4 v = p[i];
            const __half2* hh = (const __half2*)&v;
            w[r][i * 4 + 0] = hh[0];
            w[r][i * 4 + 1] = hh[1];
            w[r][i * 4 + 2] = hh[2];
            w[r][i * 4 + 3] = hh[3];
        }
        bh[r] = bhh[row];
    }

    float hj = h0 ? h0[b * H_ + j] : 0.f;
    if (c == 0) sh_h[0][j] = __float2half(hj);
    __syncthreads();

    const float* xp = xproj + b * (T_ * G3_);
    float* ob = out + b * (T_ * H_);
    float gir = xp[j], giz = xp[H_ + j], gin = xp[2 * H_ + j];

    for (int t = 0; t < T_; ++t) {
        // prefetch next step's input projections (hides HBM latency under MAC)
        const int tn = (t < T_ - 1) ? t + 1 : t;
        const float* xpn = xp + tn * G3_;
        float nr = xpn[j], nz = xpn[H_ + j], nn = xpn[2 * H_ + j];

        // MAC over this thread's K-half: 16 x ds_read_b128 + 192 hfma2
        const float4* hc = (const float4*)(&sh_h[t & 1][c * 128]);
        __half2 acc0 = __float2half2_rn(0.f);
        __half2 acc1 = __float2half2_rn(0.f);
        __half2 acc2 = __float2half2_rn(0.f);
#pragma unroll
        for (int i = 0; i < 16; ++i) {
            float4 v = hc[i];
            const __half2* hh = (const __half2*)&v;
#pragma unroll
            for (int q = 0; q < 4; ++q) {
                __half2 hv = hh[q];
                acc0 = __hfma2(w[0][i * 4 + q], hv, acc0);
                acc1 = __hfma2(w[1][i * 4 + q], hv, acc1);
                acc2 = __hfma2(w[2][i * 4 + q], hv, acc2);
            }
        }
        float p0 = __low2float(acc0) + __high2float(acc0);
        float p1 = __low2float(acc1) + __high2float(acc1);
        float p2 = __low2float(acc2) + __high2float(acc2);
        // 2-way K-reduction across lane-halves of the same wave
        float ghr = p0 + __shfl_xor(p0, 32) + bh[0];
        float ghz = p1 + __shfl_xor(p1, 32) + bh[1];
        float ghn = p2 + __shfl_xor(p2, 32) + bh[2];

        float rr = sigmoid_f(gir + ghr);
        float zz = sigmoid_f(giz + ghz);
        float nv = tanh_f(gin + rr * ghn);
        float hn = (1.f - zz) * nv + zz * hj;
        hj = hn;
        if (c == 0) {
            ob[t * H_ + j] = hn;
            sh_h[(t & 1) ^ 1][j] = __float2half(hn);
        }
        gir = nr; giz = nz; gin = nn;
        __syncthreads();
    }
    if (hT && c == 0) hT[b * H_ + j] = hj;
}

// ---- transpose k[b][s][a] -> kT[b][a][s] ----
__global__ __launch_bounds__(256) void k_transpose(const float* __restrict__ k_,
                                                   float* __restrict__ kT) {
    __shared__ float tile[64][65];
    int blk = blockIdx.x;
    int b = blk >> 4;
    int ti = (blk >> 2) & 3;
    int tj = blk & 3;
    int lane = threadIdx.x & 63;
    int ty = threadIdx.x >> 6; // 0..3
    const float* kb = k_ + b * (T_ * H_);
    for (int r = ty; r < 64; r += 4)
        tile[r][lane] = kb[(ti * 64 + r) * H_ + tj * 64 + lane];
    __syncthreads();
    float* kTb = kT + b * (T_ * H_);
    for (int r = ty; r < 64; r += 4)
        kTb[(tj * 64 + r) * T_ + ti * 64 + lane] = tile[lane][r];
}

// ---- logits[b,t,s] = mask ? v . tanh(q[b,t,:]+k[b,s,:]) : -1e9 ----
__global__ __launch_bounds__(256) void k_scores(const float* __restrict__ q,
                                                const float* __restrict__ kT,
                                                const float* __restrict__ v,
                                                const int* __restrict__ pos,
                                                float* __restrict__ out) {
    __shared__ float sq[4][256];
    __shared__ float sv[256];
    int blk = blockIdx.x;
    int b = blk >> 6;
    int t0 = (blk & 63) * 4;
    int s = threadIdx.x;
    sv[s] = v[s];
#pragma unroll
    for (int tt = 0; tt < 4; ++tt)
        sq[tt][s] = q[((b << 8) + t0 + tt) * H_ + s];
    __syncthreads();
    int ps = pos[(b << 8) + s];
    float acc[4] = {0.f, 0.f, 0.f, 0.f};
    const float* kTb = kT + b * (T_ * H_);
    for (int a = 0; a < H_; ++a) {
        float kv = kTb[a * T_ + s];
        float va = sv[a];
#pragma unroll
        for (int tt = 0; tt < 4; ++tt) {
            float th = tanh_f(sq[tt][a] + kv);
            acc[tt] += va * th;
        }
    }
#pragma unroll
    for (int tt = 0; tt < 4; ++tt) {
        int t = t0 + tt;
        out[((b << 8) + t) * T_ + s] = (t <= ps) ? acc[tt] : -1.0e9f;
    }
}

extern "C" void kernel_launch(void* const* d_in, const int* in_sizes, int n_in,
                              void* d_out, int out_size, void* d_ws, size_t ws_size,
                              hipStream_t stream) {
    (void)in_sizes; (void)n_in; (void)out_size; (void)ws_size;
    const float* inputs   = (const float*)d_in[0];
    const int* targets    = (const int*)d_in[1];  // harness passes integers as int32
    const float* W_enc   = (const float*)d_in[2];
    const float* b_enc   = (const float*)d_in[3];
    const float* enc_Wih = (const float*)d_in[4];
    const float* enc_Whh = (const float*)d_in[5];
    const float* enc_bih = (const float*)d_in[6];
    const float* enc_bhh = (const float*)d_in[7];
    const float* dec_Wih = (const float*)d_in[8];
    const float* dec_Whh = (const float*)d_in[9];
    const float* dec_bih = (const float*)d_in[10];
    const float* dec_bhh = (const float*)d_in[11];
    const float* Wq = (const float*)d_in[12];
    const float* Wk = (const float*)d_in[13];
    const float* v  = (const float*)d_in[14];
    float* out = (float*)d_out;

    float* ws = (float*)d_ws;
    float* enc_in  = ws;                 // 1,048,576 f
    float* xproj   = ws + 1048576;       // 3,145,728 f (enc then dec; later k/kT)
    float* enc_out = ws + 4194304;       // 1,048,576 f
    float* dec_out = ws + 5242880;       // 1,048,576 f
    __half2* w16e  = (__half2*)(ws + 6291456); // 98,304 dwords
    __half2* w16d  = (__half2*)(ws + 6389760); // 98,304 dwords
    float* hT      = ws + 6488064;             // 4,096 f
    int* pos       = (int*)(ws + 6492160);     // 4,096 ints
    float* q  = enc_in;          // alias: enc_in dead after dec proj
    float* kk = xproj;           // alias: xproj dead after dec GRU
    float* kT = xproj + 1048576; // alias

    k_cvtw<<<384, 256, 0, stream>>>(enc_Whh, dec_Whh, w16e, w16d);
    k_pos_init<<<16, 256, 0, stream>>>(pos);
    k_pos_scan<<<16, 256, 0, stream>>>(targets, pos);
    k_encA<<<512, 256, 0, stream>>>(inputs, W_enc, b_enc, enc_in);
    k_proj3<<<512, 256, 0, stream>>>(enc_in, enc_Wih, enc_bih, nullptr, xproj);
    k_gru<<<16, 512, 0, stream>>>(w16e, xproj, enc_bhh, nullptr, enc_out, hT);
    k_proj3<<<512, 256, 0, stream>>>(enc_in, dec_Wih, dec_bih, targets, xproj);
    k_gru<<<16, 512, 0, stream>>>(w16d, xproj, dec_bhh, hT, dec_out, nullptr);
    k_proj1<<<512, 256, 0, stream>>>(dec_out, Wq, q);
    k_proj1<<<512, 256, 0, stream>>>(enc_out, Wk, kk);
    k_transpose<<<256, 256, 0, stream>>>(kk, kT);
    k_scores<<<1024, 256, 0, stream>>>(q, kT, v, pos, out);
}